// Round 10
// baseline (248.980 us; speedup 1.0000x reference)
//
#include <hip/hip_runtime.h>

// CRF forward partition, MI355X. B=1024, L=512, T=52.
//
// R16 = R15 scatter matvec, codegen-tightened. R15 evidence: absmax 0.0
// (DPP tree + tau/rho algebra HW-verified), stall fell 472->366 (latency
// core removed) but issue ~450 cyc/wave-step (pred 210): (1) shfl_xor16
// -> ds_bpermute pair at chain end; (2) ~40KB unrolled code > 32KB L1-I
// (FETCH +640KB = refetch signature); (3) NS=8 ping-pong duplication.
// Fixes: permlane16_swap for xor16 (self-swap+select, mirrors verified
// permlane32 pattern; fallback ds_swizzle 0x401F); NS=4 single body.
//
//  - lane j owns tag tau(j) = j ^ ((j&4)?11:0); products P[r] = x*C[r],
//    col(r) = rho(r)^tau; 6-stage xor reduce-scatter, masks {1,2,8,15,16,32}
//    (= column deltas {1,2,8,4,16,32} via tau; verified R15).
//   fwd:  p'[c] = ef[c] * sum_i E[i][c] p[i]       (t = 1..256)
//   bwd:  w'[c] = sum_i E[c][i] (ef[i] w[i])       (t = 511..257)
//   out:  log(sum_c u[c]*w[c]) + shiftF + shiftB   (masked step = identity)

#define TT 52       // TAG_SIZE
#define LL 512      // sequence length
#define NS 4        // steps per group; normalize once per group

typedef float v2f __attribute__((ext_vector_type(2)));
typedef unsigned int uv2 __attribute__((ext_vector_type(2)));

__device__ __forceinline__ float rl(float x, int lane) {
    return __int_as_float(__builtin_amdgcn_readlane(__float_as_int(x), lane));
}

// Cross-lane fetch of v[lane ^ m] for m in {1,2,8,15}: DPP (verified R15).
template <int CTRL, int M>
__device__ __forceinline__ float dppx(float v) {
#if __has_builtin(__builtin_amdgcn_update_dpp)
    return __int_as_float(__builtin_amdgcn_update_dpp(
        0, __float_as_int(v), CTRL, 0xF, 0xF, true));
#else
    return __shfl_xor(v, M, 64);
#endif
}

// xor16 exchange: permlane16_swap self-swap (per 32-half: r.x=[row0|row0],
// r.y=[row1|row1]) + row-parity select. Mirrors the verified permlane32
// pattern. Fallbacks: ds_swizzle xor16 (1 DS instr), then shfl.
__device__ __forceinline__ float x16(float v, int j) {
#if __has_builtin(__builtin_amdgcn_permlane16_swap)
    uv2 r = __builtin_amdgcn_permlane16_swap(__float_as_uint(v),
                                             __float_as_uint(v), false, false);
    return ((j >> 4) & 1) ? __uint_as_float(r.x) : __uint_as_float(r.y);
#elif __has_builtin(__builtin_amdgcn_ds_swizzle)
    return __int_as_float(__builtin_amdgcn_ds_swizzle(
        __float_as_int(v), 0x401F));   // BitMode xor_mask=16, and=0x1F
#else
    return __shfl_xor(v, 16, 64);
#endif
}

// xor32 exchange via permlane32_swap (HW-verified R11/R12/R15).
__device__ __forceinline__ float xhalf(float v, bool hlo) {
#if __has_builtin(__builtin_amdgcn_permlane32_swap)
    uv2 r = __builtin_amdgcn_permlane32_swap(__float_as_uint(v),
                                             __float_as_uint(v), false, false);
    return hlo ? __uint_as_float(r.y) : __uint_as_float(r.x);
#else
    return __shfl_xor(v, 32, 64);
#endif
}

// Register layout bit-shuffle: register bits (5..0) -> column deltas
// (1,2,8,4,16,32), matching stage masks {1,2,8,15,16,32} via tau.
constexpr int rho(int r) {
    return ((r >> 5) & 1) | (((r >> 4) & 1) << 1) | (((r >> 3) & 1) << 3) |
           (((r >> 2) & 1) << 2) | (((r >> 1) & 1) << 4) | ((r & 1) << 5);
}

// Reduce-scatter matvec (verified R15): x = this lane's state entry; C2[k]
// packs coefficients for columns rho(2k)^tau, rho(2k+1)^tau. Returns the
// full column dot for this lane's own tag tau(lane).
__device__ __forceinline__ float rsmv(float x, const v2f* C2, int j, bool hlo) {
    float P[64];
#pragma unroll
    for (int k = 0; k < 32; ++k) {
        v2f xx; xx.x = x; xx.y = x;
        v2f pr = xx * C2[k];
        P[2 * k] = pr.x; P[2 * k + 1] = pr.y;
    }
#pragma unroll
    for (int r = 0; r < 32; ++r) P[r] += dppx<0xB1, 1>(P[r + 32]);   // xor1
#pragma unroll
    for (int r = 0; r < 16; ++r) P[r] += dppx<0x4E, 2>(P[r + 16]);   // xor2
#pragma unroll
    for (int r = 0; r < 8; ++r)  P[r] += dppx<0x128, 8>(P[r + 8]);   // xor8
#pragma unroll
    for (int r = 0; r < 4; ++r)  P[r] += dppx<0x140, 15>(P[r + 4]);  // xor15
#pragma unroll
    for (int r = 0; r < 2; ++r)  P[r] += x16(P[r + 2], j);           // xor16
    P[0] += xhalf(P[1], hlo);                                        // xor32
    return P[0];
}

__global__ void __launch_bounds__(128)
__attribute__((amdgpu_waves_per_eu(2, 2)))
crf_fwd(
    const float* __restrict__ feats,   // (B, L, T)
    const int*   __restrict__ mask,    // (B, L)
    const float* __restrict__ trans,   // (T, T)
    float*       __restrict__ out)     // scalar accumulator (pre-zeroed)
{
    __shared__ float plds[2][64];      // final combine only (not in loop)
    __shared__ float shsh[2];

    const int b   = blockIdx.x;
    const int tid = threadIdx.x;
    const int w   = tid >> 6;           // 0 = fwd wave, 1 = bwd wave
    const int j   = tid & 63;
    const bool hlo = (j < 32);
    const int tau = (j & 4) ? (j ^ 11) : j;   // this lane's tag
    const bool act = (j < TT);          // tau bijects {0..51}<->{0..51}
    const int tc = act ? tau : 0;       // clamped tag for safe loads

    const float* fb = feats + (size_t)b * LL * TT;
    const int*   mb = mask  + (size_t)b * LL;

    float pv;      // this wave's state entry: p[tau] (fwd) / w[tau] (bwd)
    float shift;   // log of accumulated normalization factors

    // Coefficient pack: C2[k] for columns c = rho(2k)^tau, rho(2k+1)^tau.
    //  fwd: coef = E[tau][c] = exp(trans[tau*TT + c])
    //  bwd: coef = E[c][tau] = exp(trans[c*TT + tau])
    v2f C2[32];
#pragma unroll
    for (int k = 0; k < 32; ++k) {
        int c0 = rho(2 * k) ^ tau;
        int c1 = rho(2 * k + 1) ^ tau;
        int c0c = c0 < TT ? c0 : 0;
        int c1c = c1 < TT ? c1 : 0;
        float e0, e1;
        if (w == 0) {
            e0 = __expf(trans[tc * TT + c0c]);
            e1 = __expf(trans[tc * TT + c1c]);
        } else {
            e0 = __expf(trans[c0c * TT + tc]);
            e1 = __expf(trans[c1c * TT + tc]);
        }
        C2[k].x = (act && c0 < TT) ? e0 : 0.0f;
        C2[k].y = (act && c1 < TT) ? e1 : 0.0f;
    }

    if (w == 0) {
        // ---------------- forward chain: t = 1 .. 256 ----------------
        float part0 = act ? (fb[tau] + trans[(TT - 2) * TT + tau]) : -1.0e30f;
        shift = rl(part0, 0);               // lane 0 = tag 0 (tau(0)=0)
        pv = act ? __expf(part0 - shift) : 0.0f;

        float fp[NS]; int mc[NS];
#pragma unroll
        for (int u = 0; u < NS; ++u) {
            fp[u] = fb[(1 + u) * TT + tc];
            mc[u] = mb[1 + u];
        }

        // 64 groups of 4: t = 1..256 exactly. Group g prefetches g+1
        // (t <= 260 < 512, always in-bounds).
        for (int g = 0; g < 64; ++g) {
            float fn[NS]; int mn[NS];
            int tn0 = 1 + NS * (g + 1);
#pragma unroll
            for (int u = 0; u < NS; ++u) {
                fn[u] = fb[(tn0 + u) * TT + tc];
                mn[u] = mb[tn0 + u];
            }
            float ef[NS];
#pragma unroll
            for (int u = 0; u < NS; ++u) ef[u] = __expf(fp[u]);
#pragma unroll
            for (int u = 0; u < NS; ++u) {
                float pn = rsmv(pv, C2, j, hlo) * ef[u];
                pv = (mc[u] > 0) ? pn : pv;      // branchless mask select
            }
            {   // normalize once per group by lane 0 (tag 0; > 0 always)
                float c = rl(pv, 0);
                shift += __logf(c);
                pv *= __builtin_amdgcn_rcpf(c);
            }
#pragma unroll
            for (int u = 0; u < NS; ++u) { fp[u] = fn[u]; mc[u] = mn[u]; }
        }
    } else {
        // ---------------- backward chain: t = 511 .. 257 ----------------
        pv = act ? __expf(trans[tc * TT + (TT - 1)]) : 0.0f;  // w = E[:,END]
        shift = 0.0f;

        // k = 0..254 maps to t = 511-k.
        float fp[NS]; int mc[NS];
#pragma unroll
        for (int u = 0; u < NS; ++u) {
            fp[u] = fb[(LL - 1 - u) * TT + tc];
            mc[u] = mb[LL - 1 - u];
        }

        // 63 groups of 4 (k = 0..251); tail k = 252..254. Group g
        // prefetches k = 4(g+1)..4(g+1)+3 <= 255 -> t >= 256, in-bounds.
        for (int g = 0; g < 63; ++g) {
            float fn[NS]; int mn[NS];
            int kn0 = NS * (g + 1);
#pragma unroll
            for (int u = 0; u < NS; ++u) {
                fn[u] = fb[(LL - 1 - (kn0 + u)) * TT + tc];
                mn[u] = mb[LL - 1 - (kn0 + u)];
            }
            float ef[NS];
#pragma unroll
            for (int u = 0; u < NS; ++u) ef[u] = __expf(fp[u]);
#pragma unroll
            for (int u = 0; u < NS; ++u) {
                float pn = rsmv(ef[u] * pv, C2, j, hlo);
                pv = (mc[u] > 0) ? pn : pv;      // branchless mask select
            }
            {
                float c = rl(pv, 0);
                shift += __logf(c);
                pv *= __builtin_amdgcn_rcpf(c);
            }
#pragma unroll
            for (int u = 0; u < NS; ++u) { fp[u] = fn[u]; mc[u] = mn[u]; }
        }

        // Tail: k = 252, 253, 254 (data in fp[0..2]).
#pragma unroll
        for (int u = 0; u < 3; ++u) {
            float pn = rsmv(__expf(fp[u]) * pv, C2, j, hlo);
            pv = (mc[u] > 0) ? pn : pv;
        }

        // Final safety normalize (bounds w away from inf before combine).
        {
            float c = rl(pv, 0);
            shift += __logf(c);
            pv *= __builtin_amdgcn_rcpf(c);
        }
    }

    // ------- combine: S = log(sum_c u[c]*w[c]) + shiftF + shiftB -------
    // Lane j of both waves holds tag tau(j) -> aligned products.
    plds[w][j] = pv;
    if (j == 0) shsh[w] = shift;
    __syncthreads();

    if (w == 0) {
        float wj  = plds[1][j];                  // bwd value, same tag
        float val = act ? (pv * wj) : 0.0f;
#pragma unroll
        for (int o = 32; o >= 1; o >>= 1)
            val += __shfl_xor(val, o, 64);
        if (j == 0) atomicAdd(out, __logf(val) + shift + shsh[1]);
    }
}

extern "C" void kernel_launch(void* const* d_in, const int* in_sizes, int n_in,
                              void* d_out, int out_size, void* d_ws, size_t ws_size,
                              hipStream_t stream) {
    const float* feats = (const float*)d_in[0];
    const int*   mask  = (const int*)d_in[1];
    const float* trans = (const float*)d_in[2];
    float* out = (float*)d_out;

    const int B = in_sizes[1] / LL;   // mask is (B, L)

    hipMemsetAsync(d_out, 0, sizeof(float), stream);
    crf_fwd<<<B, 128, 0, stream>>>(feats, mask, trans, out);
}